// Round 6
// baseline (273.382 us; speedup 1.0000x reference)
//
#include <hip/hip_runtime.h>
#include <math.h>

#define BB 8
#define CC 256
#define HH 128
#define WW 128
#define PP 16384  // H*W

typedef __attribute__((ext_vector_type(8))) short bf16x8;
typedef __attribute__((ext_vector_type(4))) float f32x4;
typedef unsigned long long ull;

// ---------------- ws layout (float offsets) ----------------
#define O_XNODE   0u          // B*C*H = 262144
#define O_T       262144u     // Tg 262144
#define O_R       524288u     // Rh bf16 (262144 ushort)
#define O_CTX     786432u     // Ch bf16
#define O_GT      1048576u    // Gb bf16 (2097152 ushort)
#define O_ATTR    3145728u    // B*H*W = 131072
#define O_ATTC    3276800u    // 131072
#define O_SIGMT   3567616u    // 1024
#define O_ALPHA   3568640u    // 2048
#define O_SC      3570688u    // 2048
#define O_AROW    3572736u    // 1024
#define O_ACOL    3573760u    // 1024

__device__ __forceinline__ ushort f2b(float f) {
    unsigned u = __float_as_uint(f);
    unsigned r = (u + 0x7FFFu + ((u >> 16) & 1u)) >> 16;
    return (ushort)r;
}

// block-1024 reductions: only t<256 contribute; all threads hit barriers
__device__ __forceinline__ float redSum1024(float v, float* red4, int t) {
    for (int o = 32; o; o >>= 1) v += __shfl_xor(v, o);
    __syncthreads();
    if (t < 256 && (t & 63) == 0) red4[t >> 6] = v;
    __syncthreads();
    float r = red4[0] + red4[1] + red4[2] + red4[3];
    __syncthreads();
    return r;
}
__device__ __forceinline__ float redMax1024(float v, float* red4, int t) {
    for (int o = 32; o; o >>= 1) v = fmaxf(v, __shfl_xor(v, o));
    __syncthreads();
    if (t < 256 && (t & 63) == 0) red4[t >> 6] = v;
    __syncthreads();
    float r = fmaxf(fmaxf(red4[0], red4[1]), fmaxf(red4[2], red4[3]));
    __syncthreads();
    return r;
}

// ---------- kA: X_node mean over w  (+ merged G->bf16 convert in first 1024 blocks) ----------
__global__ __launch_bounds__(256) void kA(const float* __restrict__ x, float* __restrict__ Xnode,
                                          const float* __restrict__ G, ushort* __restrict__ Gb) {
    if (blockIdx.x < 1024) {
        int i = (blockIdx.x * 256 + threadIdx.x) * 8;
        float4 v0 = *(const float4*)&G[i];
        float4 v1 = *(const float4*)&G[i + 4];
        union { ushort us[8]; uint4 u4; } o;
        o.us[0] = f2b(v0.x); o.us[1] = f2b(v0.y); o.us[2] = f2b(v0.z); o.us[3] = f2b(v0.w);
        o.us[4] = f2b(v1.x); o.us[5] = f2b(v1.y); o.us[6] = f2b(v1.z); o.us[7] = f2b(v1.w);
        *(uint4*)&Gb[i] = o.u4;
        return;
    }
    int row = (blockIdx.x - 1024) * 4 + (threadIdx.x >> 6);
    int lane = threadIdx.x & 63;
    const float2 v = *(const float2*)&x[(size_t)row * 128 + lane * 2];
    float s = v.x + v.y;
    for (int o = 32; o; o >>= 1) s += __shfl_down(s, o);
    if (lane == 0) Xnode[row] = s * (1.0f / 128.0f);
}

// ---------- kS: fused small chain (S1..S5), one block per b, 1024 threads ----------
__global__ __launch_bounds__(1024) void kS(const float* __restrict__ U, const float* __restrict__ Xnode,
                                           const float* __restrict__ reduce_w, const float* __restrict__ gcn_w,
                                           const float* __restrict__ gcn_b, const float* __restrict__ expand_w,
                                           const float* __restrict__ V, const float* __restrict__ S,
                                           const float* __restrict__ boast, const float* __restrict__ res_scale,
                                           const float* __restrict__ w_row, const float* __restrict__ w_col,
                                           float* __restrict__ Tg, float* __restrict__ sigmt,
                                           float* __restrict__ alpha, float* __restrict__ sc,
                                           float* __restrict__ arow, float* __restrict__ acol,
                                           float* __restrict__ attr, float* __restrict__ attc) {
    int b = blockIdx.x;
    int t = threadIdx.x;
    int wv = t >> 6, l = t & 63;

    __shared__ float UnL[128][17];     // padded: conflict-free column reads
    __shared__ float xrL[16][64];
    __shared__ float supL[128][64];
    __shared__ float UsumL[128];
    __shared__ float valsL[128][8];
    __shared__ int   idxL[128][8];
    __shared__ float degL[128];
    __shared__ float tmsumL[128];
    __shared__ float tmL[128];
    __shared__ float gpartL[16][64];   // per-wave partial sums of gout over i
    __shared__ float zcL[256];
    __shared__ float zkL[16];
    __shared__ float red4[4];

    // ---- P1: Un, Usum, support (wave wv handles h = it*16+wv) ----
    for (int it = 0; it < 8; ++it) {
        int h = it * 16 + wv;
        int bh = (b << 7) + h;
        float u = (l < 16) ? U[bh * 16 + l] : 0.f;
        float ss = u * u;
        for (int o = 8; o; o >>= 1) ss += __shfl_xor(ss, o, 16);
        float us = u;
        for (int o = 8; o; o >>= 1) us += __shfl_xor(us, o, 16);
        if (l < 16) UnL[h][l] = u / fmaxf(sqrtf(ss), 1e-12f);
        if (l == 0) UsumL[h] = us;
        float acc = 0.f;
        #pragma unroll
        for (int m = 0; m < 4; ++m)
            acc = fmaf(Xnode[((b * CC + l * 4 + m) << 7) + h], reduce_w[l * 4 + m], acc);
        xrL[wv][l] = acc;
        float sp = 0.f;
        for (int g = 0; g < 64; ++g) sp = fmaf(xrL[wv][g], gcn_w[g * 64 + l], sp);
        supL[h][l] = sp;
    }
    __syncthreads();

    // ---- P2: sim rows + top-8 + deg (wave per row, 2 candidates/lane) ----
    float un0[16], un1[16];
    #pragma unroll
    for (int q = 0; q < 16; ++q) { un0[q] = UnL[l][q]; un1[q] = UnL[l + 64][q]; }
    for (int it = 0; it < 8; ++it) {
        int i = it * 16 + wv;
        float s0 = 0.f, s1 = 0.f;
        #pragma unroll
        for (int q = 0; q < 16; ++q) {
            float ui = UnL[i][q];
            s0 = fmaf(ui, un0[q], s0);
            s1 = fmaf(ui, un1[q], s1);
        }
        float dsum = 0.f;
        for (int r = 0; r < 8; ++r) {
            unsigned m0 = __float_as_uint(s0); m0 = (m0 & 0x80000000u) ? ~m0 : (m0 | 0x80000000u);
            unsigned m1 = __float_as_uint(s1); m1 = (m1 & 0x80000000u) ? ~m1 : (m1 | 0x80000000u);
            ull k0 = ((ull)m0 << 32) | (0xFFFFFFFFu - (unsigned)l);
            ull k1 = ((ull)m1 << 32) | (0xFFFFFFFFu - (unsigned)(l + 64));
            ull key = k0 > k1 ? k0 : k1;
            for (int o = 32; o; o >>= 1) { ull ok = __shfl_xor(key, o); if (ok > key) key = ok; }
            int jw = (int)(0xFFFFFFFFu - (unsigned)(key & 0xFFFFFFFFull));
            unsigned mm = (unsigned)(key >> 32);
            mm = (mm & 0x80000000u) ? (mm & 0x7FFFFFFFu) : ~mm;
            float vw = __uint_as_float(mm);
            dsum += vw;
            if (l == r) { valsL[i][r] = vw; idxL[i][r] = jw; }
            if (jw == l) s0 = -3.4e38f;
            else if (jw == l + 64) s1 = -3.4e38f;
        }
        if (l == 0) degL[i] = dsum;
    }
    __syncthreads();

    // ---- P3: gcn out, Tg, tmsum, sigmt, go-partials ----
    float gp = 0.f;
    for (int it = 0; it < 8; ++it) {
        int i = it * 16 + wv;
        float rdi = 1.f / sqrtf(degL[i]);
        float acc = gcn_b[l];
        #pragma unroll
        for (int q = 0; q < 8; ++q) {
            int id = idxL[i][q];
            float dv = valsL[i][q] * rdi * (1.f / sqrtf(degL[id]));
            acc = fmaf(dv, supL[id][l], acc);
        }
        float go = fmaxf(acc, 0.f);
        gp += go;
        float e0 = expand_w[l * 4], e1 = expand_w[l * 4 + 1], e2 = expand_w[l * 4 + 2], e3 = expand_w[l * 4 + 3];
        Tg[((b * CC + l * 4 + 0) << 7) + i] = go * e0;
        Tg[((b * CC + l * 4 + 1) << 7) + i] = go * e1;
        Tg[((b * CC + l * 4 + 2) << 7) + i] = go * e2;
        Tg[((b * CC + l * 4 + 3) << 7) + i] = go * e3;
        float tms = fabsf(go) * (fabsf(e0) + fabsf(e1) + fabsf(e2) + fabsf(e3));
        float mtp = go * (e0 + e1 + e2 + e3);
        for (int o = 32; o; o >>= 1) { tms += __shfl_down(tms, o); mtp += __shfl_down(mtp, o); }
        if (l == 0) {
            tmsumL[i] = tms;
            sigmt[(b << 7) + i] = 1.f / (1.f + expf(-(mtp * (1.f / 256.f))));
        }
    }
    gpartL[wv][l] = gp;
    __syncthreads();

    // ---- P4: tm, z, ch_rec/sig, sc, w4 ----
    float tv = (t < 128) ? tmsumL[t] : -3.4e38f;
    float tmax = redMax1024(tv, red4, t);
    if (t < 128) tmL[t] = tv / fmaxf(tmax, 1e-6f);
    float zt = 0.f;
    if (t < 256) {
        const float* xn = Xnode + ((size_t)(b * CC + t) << 7);
        float zx = 0.f;
        for (int hh = 0; hh < 128; hh += 4) {
            float4 a = *(const float4*)&xn[hh];
            zx += (a.x + a.y) + (a.z + a.w);
        }
        zx *= (1.f / 128.f);
        float gs = 0.f;
        #pragma unroll
        for (int g = 0; g < 16; ++g) gs += gpartL[g][t >> 2];
        zt = expand_w[t] * gs * (1.f / 128.f);   // mean_h Tg[b,t,:]
        zcL[t] = zx + 0.5f * zt;
    }
    __syncthreads();
    if (t < 16) {
        float a = 0.f;
        for (int c = 0; c < 256; ++c) a = fmaf(zcL[c], V[((b * CC + c) << 4) + t], a);
        zkL[t] = a;
    }
    __syncthreads();
    float sig = 0.f;
    if (t < 256) {
        float sumS = 0.f, sumz = 0.f;
        #pragma unroll
        for (int j = 0; j < 16; ++j) { sumS += S[(b << 4) + j]; sumz += zkL[j]; }
        float Vz = 0.f, VS = 0.f;
        #pragma unroll
        for (int j = 0; j < 16; ++j) {
            float vv = V[((b * CC + t) << 4) + j];
            Vz = fmaf(vv, zkL[j], Vz);
            VS = fmaf(vv, S[(b << 4) + j], VS);
        }
        float ch = (Vz * sumS + VS * sumz) * (1.f / 32.f);
        sig = 1.f / (1.f + expf(-ch));
    }
    float zm = redMax1024(t < 256 ? zt : -3.4e38f, red4, t);
    float e = (t < 256) ? expf(zt - zm) : 0.f;
    float es = redSum1024(e, red4, t);
    if (t < 256) sc[b * CC + t] = e / es;
    float ps = 0.f;
    if (t < 256) {
        ps = (t < 16) ? S[(b << 4) + t] : (t < 144 ? w_col[t - 16] : w_row[t - 144]);
        if (t < 16) ps += w_row[t + 112];   // q = t+256 in [256,272)
    }
    float ssum = redSum1024(ps, red4, t);
    float l0 = -3.4e38f, l1 = -3.4e38f;
    if (t < 256) { l0 = ssum * boast[t]; l1 = ssum * boast[256 + t]; }
    float lm = redMax1024(fmaxf(l0, l1), red4, t);
    float e0 = (t < 256) ? expf(l0 - lm) : 0.f;
    float e1 = (t < 256) ? expf(l1 - lm) : 0.f;
    float esum = redSum1024(e0 + e1, red4, t);
    if (t < 128) arow[(b << 7) + t] = e0 / esum;
    else if (t < 256) acol[(b << 7) + t - 128] = e0 / esum;
    if (t < 256) alpha[b * CC + t] = res_scale[0] + (e1 / esum) * sig;
    __syncthreads();

    // ---- P5: attr (softmax over w) + attc (softmax over h), wave per row/col ----
    for (int it = 0; it < 8; ++it) {
        int r = it * 16 + wv;
        float tmr = 0.5f * tmL[r], usr = UsumL[r];
        float a0 = usr * w_row[l] + tmr;
        float a1 = usr * w_row[l + 64] + tmr;
        float m = fmaxf(a0, a1);
        for (int o = 32; o; o >>= 1) m = fmaxf(m, __shfl_xor(m, o));
        float x0 = expf(a0 - m), x1 = expf(a1 - m);
        float s = x0 + x1;
        for (int o = 32; o; o >>= 1) s += __shfl_xor(s, o);
        attr[(((b << 7) + r) << 7) + l] = x0 / s;
        attr[(((b << 7) + r) << 7) + l + 64] = x1 / s;
    }
    for (int it = 0; it < 8; ++it) {
        int w = it * 16 + wv;
        float wc = w_col[w];
        float a0 = UsumL[l] * wc + 0.5f * tmL[l];
        float a1 = UsumL[l + 64] * wc + 0.5f * tmL[l + 64];
        float m = fmaxf(a0, a1);
        for (int o = 32; o; o >>= 1) m = fmaxf(m, __shfl_xor(m, o));
        float x0 = expf(a0 - m), x1 = expf(a1 - m);
        float s = x0 + x1;
        for (int o = 32; o; o >>= 1) s += __shfl_xor(s, o);
        attc[(((b << 7) + l) << 7) + w] = x0 / s;
        attc[(((b << 7) + l + 64) << 7) + w] = x1 / s;
    }
}

// ---------- kR: R[b,c,h], Cctx[b,c,w] -> bf16  (LDS-tiled, coalesced) ----------
__global__ __launch_bounds__(256) void kR(const float* __restrict__ x, const float* __restrict__ attr,
                                          const float* __restrict__ attc, ushort* __restrict__ Rh,
                                          ushort* __restrict__ Ch) {
    int bc = blockIdx.x;
    int b = bc >> 8;
    int t = threadIdx.x;
    __shared__ float tile[64][132];
    __shared__ float rsum[64][5];
    __shared__ float cred[8][128];
    int wq = (t & 31) * 4;
    int hg = t >> 5;
    const float* xb  = x    + (size_t)bc * PP;
    const float* arb = attr + (size_t)b * PP;
    const float* acb = attc + (size_t)b * PP;
    float4 cacc = make_float4(0.f, 0.f, 0.f, 0.f);
    #pragma unroll
    for (int cchunk = 0; cchunk < 2; ++cchunk) {
        int h0 = cchunk * 64;
        #pragma unroll
        for (int i = 0; i < 8; ++i) {
            int hh = i * 8 + hg;
            int off = (h0 + hh) * 128 + wq;
            float4 xv  = *(const float4*)&xb[off];
            float4 ar4 = *(const float4*)&arb[off];
            float4 ac4 = *(const float4*)&acb[off];
            cacc.x = fmaf(ac4.x, xv.x, cacc.x);
            cacc.y = fmaf(ac4.y, xv.y, cacc.y);
            cacc.z = fmaf(ac4.z, xv.z, cacc.z);
            cacc.w = fmaf(ac4.w, xv.w, cacc.w);
            float4 pr;
            pr.x = ar4.x * xv.x; pr.y = ar4.y * xv.y; pr.z = ar4.z * xv.z; pr.w = ar4.w * xv.w;
            *(float4*)&tile[hh][wq] = pr;
        }
        __syncthreads();
        int hl = t & 63, q = t >> 6;
        float s = 0.f;
        #pragma unroll
        for (int j = 0; j < 8; ++j) {
            float4 v = *(const float4*)&tile[hl][q * 32 + j * 4];
            s += (v.x + v.y) + (v.z + v.w);
        }
        rsum[hl][q] = s;
        __syncthreads();
        if (t < 64) Rh[bc * 128 + h0 + t] = f2b(rsum[t][0] + rsum[t][1] + rsum[t][2] + rsum[t][3]);
        __syncthreads();
    }
    *(float4*)&cred[hg][wq] = cacc;
    __syncthreads();
    if (t < 128) {
        float s = 0.f;
        #pragma unroll
        for (int g = 0; g < 8; ++g) s += cred[g][t];
        Ch[bc * 128 + t] = f2b(s);
    }
}

// ---------- kF: MFMA GEMM + epilogue (round-3 structure + x/scalar prefetch) ----------
// block: 64c x 128p (one h row), 4 waves; A=G (rows=p), B=R/C (rows=c).
// D: col=lane&15 -> c, row=4*(lane>>4)+reg -> p  => per-lane float4 over consecutive p.
__global__ __launch_bounds__(256) void kF(const float* __restrict__ x, const ushort* __restrict__ Rh,
                                          const ushort* __restrict__ Ch, const ushort* __restrict__ Gb,
                                          const float* __restrict__ Tg, const float* __restrict__ alpha,
                                          const float* __restrict__ sc, const float* __restrict__ sigmt,
                                          const float* __restrict__ arow, const float* __restrict__ acol,
                                          float* __restrict__ out) {
    int b = blockIdx.z;
    int c0 = blockIdx.y * 64;
    int p0 = blockIdx.x * 128;
    int tid = threadIdx.x;
    int wid = tid >> 6, l = tid & 63;
    int lr = l & 15, lk = l >> 4;
    int pbase = p0 + (wid & 1) * 64;
    int cbase = c0 + (wid >> 1) * 32;
    int h = blockIdx.x;

    // prefetch x + per-c scalars FIRST: they drain during the MFMA phase
    f32x4 xv[2][4];
    float al[2], scv[2], tgv[2];
    size_t rowb[2];
    #pragma unroll
    for (int n = 0; n < 2; ++n) {
        int c = cbase + 16 * n + lr;
        rowb[n] = ((size_t)((b << 8) + c) << 14) + pbase + 4 * lk;
        #pragma unroll
        for (int m = 0; m < 4; ++m)
            xv[n][m] = *(const f32x4*)&x[rowb[n] + 16 * m];
        al[n] = alpha[(b << 8) + c];
        scv[n] = sc[(b << 8) + c];
        tgv[n] = Tg[(((b << 8) + c) << 7) + h];
    }
    float ar = arow[(b << 7) + h];
    float smt = sigmt[(b << 7) + h];
    int wloc = (wid & 1) * 64 + 4 * lk;
    f32x4 acw[4];
    #pragma unroll
    for (int m = 0; m < 4; ++m) acw[m] = *(const f32x4*)&acol[(b << 7) + wloc + 16 * m];

    f32x4 accR[4][2], accC[4][2];
    #pragma unroll
    for (int m = 0; m < 4; ++m)
        #pragma unroll
        for (int n = 0; n < 2; ++n) {
            accR[m][n] = (f32x4){0.f, 0.f, 0.f, 0.f};
            accC[m][n] = (f32x4){0.f, 0.f, 0.f, 0.f};
        }

    const ushort* Gbase = Gb + ((size_t)(pbase + lr) << 7);
    const ushort* Rbase = Rh + (((b << 8) + cbase + lr) << 7);
    const ushort* Cbase = Ch + (((b << 8) + cbase + lr) << 7);

    #pragma unroll
    for (int ks = 0; ks < 4; ++ks) {
        int ko = ks * 32 + lk * 8;
        bf16x8 ag0 = *(const bf16x8*)(Gbase + (0 << 11) + ko);
        bf16x8 ag1 = *(const bf16x8*)(Gbase + (1 << 11) + ko);
        bf16x8 ag2 = *(const bf16x8*)(Gbase + (2 << 11) + ko);
        bf16x8 ag3 = *(const bf16x8*)(Gbase + (3 << 11) + ko);
        bf16x8 bR0 = *(const bf16x8*)(Rbase + ko);
        bf16x8 bR1 = *(const bf16x8*)(Rbase + (16 << 7) + ko);
        bf16x8 bC0 = *(const bf16x8*)(Cbase + ko);
        bf16x8 bC1 = *(const bf16x8*)(Cbase + (16 << 7) + ko);
        accR[0][0] = __builtin_amdgcn_mfma_f32_16x16x32_bf16(ag0, bR0, accR[0][0], 0, 0, 0);
        accR[0][1] = __builtin_amdgcn_mfma_f32_16x16x32_bf16(ag0, bR1, accR[0][1], 0, 0, 0);
        accR[1][0] = __builtin_amdgcn_mfma_f32_16x16x32_bf16(ag1, bR0, accR[1][0], 0, 0, 0);
        accR[1][1] = __builtin_amdgcn_mfma_f32_16x16x32_bf16(ag1, bR1, accR[1][1], 0, 0, 0);
        accR[2][0] = __builtin_amdgcn_mfma_f32_16x16x32_bf16(ag2, bR0, accR[2][0], 0, 0, 0);
        accR[2][1] = __builtin_amdgcn_mfma_f32_16x16x32_bf16(ag2, bR1, accR[2][1], 0, 0, 0);
        accR[3][0] = __builtin_amdgcn_mfma_f32_16x16x32_bf16(ag3, bR0, accR[3][0], 0, 0, 0);
        accR[3][1] = __builtin_amdgcn_mfma_f32_16x16x32_bf16(ag3, bR1, accR[3][1], 0, 0, 0);
        accC[0][0] = __builtin_amdgcn_mfma_f32_16x16x32_bf16(ag0, bC0, accC[0][0], 0, 0, 0);
        accC[0][1] = __builtin_amdgcn_mfma_f32_16x16x32_bf16(ag0, bC1, accC[0][1], 0, 0, 0);
        accC[1][0] = __builtin_amdgcn_mfma_f32_16x16x32_bf16(ag1, bC0, accC[1][0], 0, 0, 0);
        accC[1][1] = __builtin_amdgcn_mfma_f32_16x16x32_bf16(ag1, bC1, accC[1][1], 0, 0, 0);
        accC[2][0] = __builtin_amdgcn_mfma_f32_16x16x32_bf16(ag2, bC0, accC[2][0], 0, 0, 0);
        accC[2][1] = __builtin_amdgcn_mfma_f32_16x16x32_bf16(ag2, bC1, accC[2][1], 0, 0, 0);
        accC[3][0] = __builtin_amdgcn_mfma_f32_16x16x32_bf16(ag3, bC0, accC[3][0], 0, 0, 0);
        accC[3][1] = __builtin_amdgcn_mfma_f32_16x16x32_bf16(ag3, bC1, accC[3][1], 0, 0, 0);
    }

    #pragma unroll
    for (int n = 0; n < 2; ++n) {
        float tb = (scv[n] + smt) * tgv[n];
        #pragma unroll
        for (int m = 0; m < 4; ++m) {
            f32x4 o;
            o[0] = fmaf(al[n], xv[n][m][0], fmaf(ar, accR[m][n][0], fmaf(acw[m][0], accC[m][n][0], ar * acw[m][0] * tb)));
            o[1] = fmaf(al[n], xv[n][m][1], fmaf(ar, accR[m][n][1], fmaf(acw[m][1], accC[m][n][1], ar * acw[m][1] * tb)));
            o[2] = fmaf(al[n], xv[n][m][2], fmaf(ar, accR[m][n][2], fmaf(acw[m][2], accC[m][n][2], ar * acw[m][2] * tb)));
            o[3] = fmaf(al[n], xv[n][m][3], fmaf(ar, accR[m][n][3], fmaf(acw[m][3], accC[m][n][3], ar * acw[m][3] * tb)));
            *(f32x4*)&out[rowb[n] + 16 * m] = o;
        }
    }
}

extern "C" void kernel_launch(void* const* d_in, const int* in_sizes, int n_in,
                              void* d_out, int out_size, void* d_ws, size_t ws_size,
                              hipStream_t stream) {
    const float* x        = (const float*)d_in[0];
    const float* U        = (const float*)d_in[1];
    const float* S        = (const float*)d_in[2];
    const float* V        = (const float*)d_in[3];
    const float* G        = (const float*)d_in[4];
    const float* w_row    = (const float*)d_in[5];
    const float* w_col    = (const float*)d_in[6];
    const float* boast    = (const float*)d_in[7];
    const float* res_scale= (const float*)d_in[8];
    const float* reduce_w = (const float*)d_in[9];
    const float* gcn_w    = (const float*)d_in[10];
    const float* gcn_b    = (const float*)d_in[11];
    const float* expand_w = (const float*)d_in[12];
    float* ws = (float*)d_ws;
    float* out = (float*)d_out;

    float* Xnode = ws + O_XNODE;
    float* Tg    = ws + O_T;
    ushort* Rh   = (ushort*)(ws + O_R);
    ushort* Ch   = (ushort*)(ws + O_CTX);
    ushort* Gb   = (ushort*)(ws + O_GT);
    float* attr  = ws + O_ATTR;
    float* attc  = ws + O_ATTC;
    float* sigmt = ws + O_SIGMT;
    float* alpha = ws + O_ALPHA;
    float* sc    = ws + O_SC;
    float* arow  = ws + O_AROW;
    float* acol  = ws + O_ACOL;

    kA<<<1024 + BB * CC * HH / 4, 256, 0, stream>>>(x, Xnode, G, Gb);
    kS<<<BB, 1024, 0, stream>>>(U, Xnode, reduce_w, gcn_w, gcn_b, expand_w, V, S,
                                boast, res_scale, w_row, w_col,
                                Tg, sigmt, alpha, sc, arow, acol, attr, attc);
    kR<<<BB * CC, 256, 0, stream>>>(x, attr, attc, Rh, Ch);
    kF<<<dim3(PP / 128, CC / 64, BB), 256, 0, stream>>>(x, Rh, Ch, Gb, Tg, alpha, sc, sigmt,
                                                        arow, acol, out);
}

// Round 7
// 196.501 us; speedup vs baseline: 1.3912x; 1.3912x over previous
//
#include <hip/hip_runtime.h>
#include <math.h>

#define BB 8
#define CC 256
#define HH 128
#define WW 128
#define PP 16384  // H*W

typedef __attribute__((ext_vector_type(8))) short bf16x8;
typedef __attribute__((ext_vector_type(4))) float f32x4;

// ---------------- ws layout (float offsets) ----------------
#define O_XNODE   0u          // B*C*H = 262144
#define O_T       262144u     // 262144
#define O_R       524288u     // Rh bf16 (262144 ushort)
#define O_CTX     786432u     // Ch bf16
#define O_GT      1048576u    // Gb bf16 (2097152 ushort)
#define O_ATTR    3145728u    // B*H*W = 131072
#define O_ATTC    3276800u    // 131072
#define O_UN      3407872u    // B*H*16 = 16384
#define O_SUP     3424256u    // B*H*64 = 65536
#define O_VALS    3555328u    // B*H*8 = 8192
#define O_DEG     3563520u    // 1024
#define O_USUM    3564544u    // 1024
#define O_TMSUM   3565568u    // 1024
#define O_TM      3566592u    // 1024
#define O_SIGMT   3567616u    // 1024
#define O_ALPHA   3568640u    // 2048
#define O_SC      3570688u    // 2048
#define O_AROW    3572736u    // 1024
#define O_ACOL    3573760u    // 1024
#define O_IDX     3574784u    // 8192 ints

__device__ __forceinline__ ushort f2b(float f) {
    unsigned u = __float_as_uint(f);
    unsigned r = (u + 0x7FFFu + ((u >> 16) & 1u)) >> 16;
    return (ushort)r;
}

__device__ __forceinline__ float bredSum256(float v, float* red) {
    int t = threadIdx.x, lane = t & 63, wv = t >> 6;
    for (int o = 32; o; o >>= 1) v += __shfl_xor(v, o);
    __syncthreads();
    if (lane == 0) red[wv] = v;
    __syncthreads();
    return red[0] + red[1] + red[2] + red[3];
}
__device__ __forceinline__ float bredMax256(float v, float* red) {
    int t = threadIdx.x, lane = t & 63, wv = t >> 6;
    for (int o = 32; o; o >>= 1) v = fmaxf(v, __shfl_xor(v, o));
    __syncthreads();
    if (lane == 0) red[wv] = v;
    __syncthreads();
    return fmaxf(fmaxf(red[0], red[1]), fmaxf(red[2], red[3]));
}

// ---------- kA: X_node mean over w  (+ merged G->bf16 convert in first 1024 blocks) ----------
__global__ __launch_bounds__(256) void kA(const float* __restrict__ x, float* __restrict__ Xnode,
                                          const float* __restrict__ G, ushort* __restrict__ Gb) {
    if (blockIdx.x < 1024) {
        int i = (blockIdx.x * 256 + threadIdx.x) * 8;
        float4 v0 = *(const float4*)&G[i];
        float4 v1 = *(const float4*)&G[i + 4];
        union { ushort us[8]; uint4 u4; } o;
        o.us[0] = f2b(v0.x); o.us[1] = f2b(v0.y); o.us[2] = f2b(v0.z); o.us[3] = f2b(v0.w);
        o.us[4] = f2b(v1.x); o.us[5] = f2b(v1.y); o.us[6] = f2b(v1.z); o.us[7] = f2b(v1.w);
        *(uint4*)&Gb[i] = o.u4;
        return;
    }
    int row = (blockIdx.x - 1024) * 4 + (threadIdx.x >> 6);
    int lane = threadIdx.x & 63;
    const float2 v = *(const float2*)&x[(size_t)row * 128 + lane * 2];
    float s = v.x + v.y;
    for (int o = 32; o; o >>= 1) s += __shfl_down(s, o);
    if (lane == 0) Xnode[row] = s * (1.0f / 128.0f);
}

// ---------- S1: Un, Usum, support (per b,h) ----------
__global__ __launch_bounds__(64) void kS1(const float* __restrict__ U, const float* __restrict__ Xnode,
                                          const float* __restrict__ reduce_w, const float* __restrict__ gcn_w,
                                          float* __restrict__ Un, float* __restrict__ Usum, float* __restrict__ sup) {
    int bh = blockIdx.x; int b = bh >> 7, h = bh & 127;
    int t = threadIdx.x;
    __shared__ float xr[64];
    float u = (t < 16) ? U[bh * 16 + t] : 0.f;
    float ss = u * u;
    for (int o = 8; o; o >>= 1) ss += __shfl_xor(ss, o, 16);
    float us = u;
    for (int o = 8; o; o >>= 1) us += __shfl_xor(us, o, 16);
    if (t < 16) Un[bh * 16 + t] = u / fmaxf(sqrtf(ss), 1e-12f);
    if (t == 0) Usum[bh] = us;
    float acc = 0.f;
    #pragma unroll
    for (int m = 0; m < 4; ++m)
        acc = fmaf(Xnode[((b * CC + t * 4 + m) << 7) + h], reduce_w[t * 4 + m], acc);
    xr[t] = acc;
    __syncthreads();
    float sp = 0.f;
    for (int g = 0; g < 64; ++g) sp = fmaf(xr[g], gcn_w[g * 64 + t], sp);
    sup[bh * 64 + t] = sp;
}

// ---------- S2: sim row + top-8 + deg (per b,i) ----------
__global__ __launch_bounds__(128) void kS2(const float* __restrict__ Un, float* __restrict__ vals,
                                           int* __restrict__ idxv, float* __restrict__ deg) {
    int bh = blockIdx.x; int b = bh >> 7;
    int t = threadIdx.x;
    __shared__ float uni[16];
    __shared__ unsigned long long wmax[2];
    if (t < 16) uni[t] = Un[bh * 16 + t];
    __syncthreads();
    const float* uj = Un + (b << 11) + t * 16;
    float s = 0.f;
    #pragma unroll
    for (int q = 0; q < 16; ++q) s = fmaf(uni[q], uj[q], s);
    float dsum = 0.f;
    for (int r = 0; r < 8; ++r) {
        unsigned m = __float_as_uint(s);
        m = (m & 0x80000000u) ? ~m : (m | 0x80000000u);
        unsigned long long key = ((unsigned long long)m << 32) | (unsigned)(0xFFFFFFFFu - (unsigned)t);
        for (int o = 32; o; o >>= 1) { unsigned long long ok = __shfl_xor(key, o); key = key > ok ? key : ok; }
        if ((t & 63) == 0) wmax[t >> 6] = key;
        __syncthreads();
        unsigned long long kk = wmax[0] > wmax[1] ? wmax[0] : wmax[1];
        __syncthreads();
        int jw = (int)(0xFFFFFFFFu - (unsigned)(kk & 0xFFFFFFFFu));
        unsigned mm = (unsigned)(kk >> 32);
        mm = (mm & 0x80000000u) ? (mm & 0x7FFFFFFFu) : ~mm;
        float vw = __uint_as_float(mm);
        dsum += vw;
        if (t == r) { vals[bh * 8 + r] = vw; idxv[bh * 8 + r] = jw; }
        if (t == jw) s = -3.4e38f;
    }
    if (t == 0) deg[bh] = dsum;
}

// ---------- S3: gout, T, tmsum, sigmt (per b,i) ----------
__global__ __launch_bounds__(64) void kS3(const float* __restrict__ vals, const int* __restrict__ idxv,
                                          const float* __restrict__ deg, const float* __restrict__ sup,
                                          const float* __restrict__ gcn_b, const float* __restrict__ expand_w,
                                          float* __restrict__ Tg,
                                          float* __restrict__ tmsum, float* __restrict__ sigmt) {
    int bh = blockIdx.x; int b = bh >> 7, i = bh & 127;
    int t = threadIdx.x;
    __shared__ float coef[8];
    __shared__ int id[8];
    if (t < 8) {
        int j = idxv[bh * 8 + t];
        float dv = vals[bh * 8 + t] * (1.f / sqrtf(deg[bh])) * (1.f / sqrtf(deg[(b << 7) + j]));
        coef[t] = dv; id[t] = j;
    }
    __syncthreads();
    float acc = gcn_b[t];
    #pragma unroll
    for (int q = 0; q < 8; ++q) acc = fmaf(coef[q], sup[((b << 7) + id[q]) * 64 + t], acc);
    float go = fmaxf(acc, 0.f);
    float e0 = expand_w[t * 4], e1 = expand_w[t * 4 + 1], e2 = expand_w[t * 4 + 2], e3 = expand_w[t * 4 + 3];
    Tg[((b * CC + t * 4 + 0) << 7) + i] = go * e0;
    Tg[((b * CC + t * 4 + 1) << 7) + i] = go * e1;
    Tg[((b * CC + t * 4 + 2) << 7) + i] = go * e2;
    Tg[((b * CC + t * 4 + 3) << 7) + i] = go * e3;
    float tms = fabsf(go) * (fabsf(e0) + fabsf(e1) + fabsf(e2) + fabsf(e3));
    float mtp = go * (e0 + e1 + e2 + e3);
    for (int o = 32; o; o >>= 1) { tms += __shfl_down(tms, o); mtp += __shfl_down(mtp, o); }
    if (t == 0) {
        tmsum[bh] = tms;
        sigmt[bh] = 1.f / (1.f + expf(-(mtp * (1.f / 256.f))));
    }
}

// ---------- S4: tm, z's, ch_rec/sig, sc, w4 -> arow/acol/alpha (per b) ----------
__global__ __launch_bounds__(256) void kS4(const float* __restrict__ Xnode, const float* __restrict__ Tg,
                                           const float* __restrict__ V, const float* __restrict__ S,
                                           const float* __restrict__ boast, const float* __restrict__ res_scale,
                                           const float* __restrict__ w_row, const float* __restrict__ w_col,
                                           const float* __restrict__ tmsum,
                                           float* __restrict__ tm, float* __restrict__ alpha, float* __restrict__ sc,
                                           float* __restrict__ arow, float* __restrict__ acol) {
    int b = blockIdx.x; int t = threadIdx.x;
    __shared__ float red[4];
    __shared__ float zc[256];
    __shared__ float zk[16];
    float tv = (t < 128) ? tmsum[(b << 7) + t] : -3.4e38f;
    float tmax = bredMax256(tv, red);
    if (t < 128) tm[(b << 7) + t] = tv / fmaxf(tmax, 1e-6f);
    const float* xn = Xnode + ((size_t)(b * CC + t) << 7);
    const float* tg = Tg + ((size_t)(b * CC + t) << 7);
    float zx = 0.f, zt = 0.f;
    for (int h = 0; h < 128; h += 4) {
        float4 a = *(const float4*)&xn[h];
        float4 bq = *(const float4*)&tg[h];
        zx += (a.x + a.y) + (a.z + a.w);
        zt += (bq.x + bq.y) + (bq.z + bq.w);
    }
    zx *= (1.f / 128.f); zt *= (1.f / 128.f);
    zc[t] = zx + 0.5f * zt;
    __syncthreads();
    if (t < 16) {
        float a = 0.f;
        for (int c = 0; c < 256; ++c) a = fmaf(zc[c], V[((b * CC + c) << 4) + t], a);
        zk[t] = a;
    }
    __syncthreads();
    float sumS = 0.f, sumz = 0.f;
    #pragma unroll
    for (int j = 0; j < 16; ++j) { sumS += S[(b << 4) + j]; sumz += zk[j]; }
    float Vz = 0.f, VS = 0.f;
    #pragma unroll
    for (int j = 0; j < 16; ++j) {
        float vv = V[((b * CC + t) << 4) + j];
        Vz = fmaf(vv, zk[j], Vz);
        VS = fmaf(vv, S[(b << 4) + j], VS);
    }
    float ch = (Vz * sumS + VS * sumz) * (1.f / 32.f);
    float sig = 1.f / (1.f + expf(-ch));
    float zm = bredMax256(zt, red);
    float e = expf(zt - zm);
    float es = bredSum256(e, red);
    sc[b * CC + t] = e / es;
    float ps = 0.f;
    for (int q = t; q < 272; q += 256) {
        float si = (q < 16) ? S[(b << 4) + q] : (q < 144 ? w_col[q - 16] : w_row[q - 144]);
        ps += si;
    }
    float ssum = bredSum256(ps, red);
    float l0 = ssum * boast[t];
    float l1 = ssum * boast[256 + t];
    float lm = bredMax256(fmaxf(l0, l1), red);
    float e0 = expf(l0 - lm), e1 = expf(l1 - lm);
    float esum = bredSum256(e0 + e1, red);
    float w40 = e0 / esum, w41 = e1 / esum;
    if (t < 128) arow[(b << 7) + t] = w40;
    else acol[(b << 7) + (t - 128)] = w40;
    alpha[b * CC + t] = res_scale[0] + w41 * sig;
}

// ---------- S5: merged row/col softmax ----------
__global__ __launch_bounds__(128) void kS5(const float* __restrict__ Usum, const float* __restrict__ w_row,
                                           const float* __restrict__ w_col, const float* __restrict__ tm,
                                           float* __restrict__ attr, float* __restrict__ attc) {
    __shared__ float red[2];
    int id = blockIdx.x;
    int t = threadIdx.x;
    if (id < BB * HH) {
        int bh = id;
        float l = Usum[bh] * w_row[t] + 0.5f * tm[bh];
        float m = l;
        for (int o = 32; o; o >>= 1) m = fmaxf(m, __shfl_xor(m, o));
        if ((t & 63) == 0) red[t >> 6] = m;
        __syncthreads();
        m = fmaxf(red[0], red[1]);
        __syncthreads();
        float e = expf(l - m);
        float s = e;
        for (int o = 32; o; o >>= 1) s += __shfl_xor(s, o);
        if ((t & 63) == 0) red[t >> 6] = s;
        __syncthreads();
        s = red[0] + red[1];
        attr[id * 128 + t] = e / s;
    } else {
        int bw = id - BB * HH; int b = bw >> 7, w = bw & 127;
        float l = Usum[(b << 7) + t] * w_col[w] + 0.5f * tm[(b << 7) + t];
        float m = l;
        for (int o = 32; o; o >>= 1) m = fmaxf(m, __shfl_xor(m, o));
        if ((t & 63) == 0) red[t >> 6] = m;
        __syncthreads();
        m = fmaxf(red[0], red[1]);
        __syncthreads();
        float e = expf(l - m);
        float s = e;
        for (int o = 32; o; o >>= 1) s += __shfl_xor(s, o);
        if ((t & 63) == 0) red[t >> 6] = s;
        __syncthreads();
        s = red[0] + red[1];
        attc[((b << 7) + t) * 128 + w] = e / s;
    }
}

// ---------- kR: R[b,c,h], Cctx[b,c,w] -> bf16  (LDS-tiled, coalesced) ----------
__global__ __launch_bounds__(256) void kR(const float* __restrict__ x, const float* __restrict__ attr,
                                          const float* __restrict__ attc, ushort* __restrict__ Rh,
                                          ushort* __restrict__ Ch) {
    int bc = blockIdx.x;
    int b = bc >> 8;
    int t = threadIdx.x;
    __shared__ float tile[64][132];
    __shared__ float rsum[64][5];
    __shared__ float cred[8][128];
    int wq = (t & 31) * 4;
    int hg = t >> 5;
    const float* xb  = x    + (size_t)bc * PP;
    const float* arb = attr + (size_t)b * PP;
    const float* acb = attc + (size_t)b * PP;
    float4 cacc = make_float4(0.f, 0.f, 0.f, 0.f);
    #pragma unroll
    for (int cchunk = 0; cchunk < 2; ++cchunk) {
        int h0 = cchunk * 64;
        #pragma unroll
        for (int i = 0; i < 8; ++i) {
            int hh = i * 8 + hg;
            int off = (h0 + hh) * 128 + wq;
            float4 xv  = *(const float4*)&xb[off];
            float4 ar4 = *(const float4*)&arb[off];
            float4 ac4 = *(const float4*)&acb[off];
            cacc.x = fmaf(ac4.x, xv.x, cacc.x);
            cacc.y = fmaf(ac4.y, xv.y, cacc.y);
            cacc.z = fmaf(ac4.z, xv.z, cacc.z);
            cacc.w = fmaf(ac4.w, xv.w, cacc.w);
            float4 pr;
            pr.x = ar4.x * xv.x; pr.y = ar4.y * xv.y; pr.z = ar4.z * xv.z; pr.w = ar4.w * xv.w;
            *(float4*)&tile[hh][wq] = pr;
        }
        __syncthreads();
        int hl = t & 63, q = t >> 6;
        float s = 0.f;
        #pragma unroll
        for (int j = 0; j < 8; ++j) {
            float4 v = *(const float4*)&tile[hl][q * 32 + j * 4];
            s += (v.x + v.y) + (v.z + v.w);
        }
        rsum[hl][q] = s;
        __syncthreads();
        if (t < 64) Rh[bc * 128 + h0 + t] = f2b(rsum[t][0] + rsum[t][1] + rsum[t][2] + rsum[t][3]);
        __syncthreads();
    }
    *(float4*)&cred[hg][wq] = cacc;
    __syncthreads();
    if (t < 128) {
        float s = 0.f;
        #pragma unroll
        for (int g = 0; g < 8; ++g) s += cred[g][t];
        Ch[bc * 128 + t] = f2b(s);
    }
}

// ---------- kF: MFMA GEMM + epilogue (R5 version: x/scalar prefetch before frags) ----------
__global__ __launch_bounds__(256) void kF(const float* __restrict__ x, const ushort* __restrict__ Rh,
                                          const ushort* __restrict__ Ch, const ushort* __restrict__ Gb,
                                          const float* __restrict__ Tg, const float* __restrict__ alpha,
                                          const float* __restrict__ sc, const float* __restrict__ sigmt,
                                          const float* __restrict__ arow, const float* __restrict__ acol,
                                          float* __restrict__ out) {
    int b = blockIdx.z;
    int c0 = blockIdx.y * 64;
    int p0 = blockIdx.x * 128;
    int tid = threadIdx.x;
    int wid = tid >> 6, l = tid & 63;
    int lr = l & 15, lk = l >> 4;
    int pbase = p0 + (wid & 1) * 64;
    int cbase = c0 + (wid >> 1) * 32;
    int h = blockIdx.x;

    f32x4 xv[2][4];
    float al[2], scv[2], tgv[2];
    size_t rowb[2];
    #pragma unroll
    for (int n = 0; n < 2; ++n) {
        int c = cbase + 16 * n + lr;
        rowb[n] = ((size_t)((b << 8) + c) << 14) + pbase + 4 * lk;
        #pragma unroll
        for (int m = 0; m < 4; ++m)
            xv[n][m] = *(const f32x4*)&x[rowb[n] + 16 * m];
        al[n] = alpha[(b << 8) + c];
        scv[n] = sc[(b << 8) + c];
        tgv[n] = Tg[(((b << 8) + c) << 7) + h];
    }
    float ar = arow[(b << 7) + h];
    float smt = sigmt[(b << 7) + h];
    int wloc = (wid & 1) * 64 + 4 * lk;
    f32x4 acw[4];
    #pragma unroll
    for (int m = 0; m < 4; ++m) acw[m] = *(const f32x4*)&acol[(b << 7) + wloc + 16 * m];

    f32x4 accR[4][2], accC[4][2];
    #pragma unroll
    for (int m = 0; m < 4; ++m)
        #pragma unroll
        for (int n = 0; n < 2; ++n) {
            accR[m][n] = (f32x4){0.f, 0.f, 0.f, 0.f};
            accC[m][n] = (f32x4){0.f, 0.f, 0.f, 0.f};
        }

    const ushort* Gbase = Gb + ((size_t)(pbase + lr) << 7);
    const ushort* Rbase = Rh + (((b << 8) + cbase + lr) << 7);
    const ushort* Cbase = Ch + (((b << 8) + cbase + lr) << 7);

    #pragma unroll
    for (int ks = 0; ks < 4; ++ks) {
        int ko = ks * 32 + lk * 8;
        bf16x8 ag0 = *(const bf16x8*)(Gbase + (0 << 11) + ko);
        bf16x8 ag1 = *(const bf16x8*)(Gbase + (1 << 11) + ko);
        bf16x8 ag2 = *(const bf16x8*)(Gbase + (2 << 11) + ko);
        bf16x8 ag3 = *(const bf16x8*)(Gbase + (3 << 11) + ko);
        bf16x8 bR0 = *(const bf16x8*)(Rbase + ko);
        bf16x8 bR1 = *(const bf16x8*)(Rbase + (16 << 7) + ko);
        bf16x8 bC0 = *(const bf16x8*)(Cbase + ko);
        bf16x8 bC1 = *(const bf16x8*)(Cbase + (16 << 7) + ko);
        accR[0][0] = __builtin_amdgcn_mfma_f32_16x16x32_bf16(ag0, bR0, accR[0][0], 0, 0, 0);
        accR[0][1] = __builtin_amdgcn_mfma_f32_16x16x32_bf16(ag0, bR1, accR[0][1], 0, 0, 0);
        accR[1][0] = __builtin_amdgcn_mfma_f32_16x16x32_bf16(ag1, bR0, accR[1][0], 0, 0, 0);
        accR[1][1] = __builtin_amdgcn_mfma_f32_16x16x32_bf16(ag1, bR1, accR[1][1], 0, 0, 0);
        accR[2][0] = __builtin_amdgcn_mfma_f32_16x16x32_bf16(ag2, bR0, accR[2][0], 0, 0, 0);
        accR[2][1] = __builtin_amdgcn_mfma_f32_16x16x32_bf16(ag2, bR1, accR[2][1], 0, 0, 0);
        accR[3][0] = __builtin_amdgcn_mfma_f32_16x16x32_bf16(ag3, bR0, accR[3][0], 0, 0, 0);
        accR[3][1] = __builtin_amdgcn_mfma_f32_16x16x32_bf16(ag3, bR1, accR[3][1], 0, 0, 0);
        accC[0][0] = __builtin_amdgcn_mfma_f32_16x16x32_bf16(ag0, bC0, accC[0][0], 0, 0, 0);
        accC[0][1] = __builtin_amdgcn_mfma_f32_16x16x32_bf16(ag0, bC1, accC[0][1], 0, 0, 0);
        accC[1][0] = __builtin_amdgcn_mfma_f32_16x16x32_bf16(ag1, bC0, accC[1][0], 0, 0, 0);
        accC[1][1] = __builtin_amdgcn_mfma_f32_16x16x32_bf16(ag1, bC1, accC[1][1], 0, 0, 0);
        accC[2][0] = __builtin_amdgcn_mfma_f32_16x16x32_bf16(ag2, bC0, accC[2][0], 0, 0, 0);
        accC[2][1] = __builtin_amdgcn_mfma_f32_16x16x32_bf16(ag2, bC1, accC[2][1], 0, 0, 0);
        accC[3][0] = __builtin_amdgcn_mfma_f32_16x16x32_bf16(ag3, bC0, accC[3][0], 0, 0, 0);
        accC[3][1] = __builtin_amdgcn_mfma_f32_16x16x32_bf16(ag3, bC1, accC[3][1], 0, 0, 0);
    }

    #pragma unroll
    for (int n = 0; n < 2; ++n) {
        float tb = (scv[n] + smt) * tgv[n];
        #pragma unroll
        for (int m = 0; m < 4; ++m) {
            f32x4 o;
            o[0] = fmaf(al[n], xv[n][m][0], fmaf(ar, accR[m][n][0], fmaf(acw[m][0], accC[m][n][0], ar * acw[m][0] * tb)));
            o[1] = fmaf(al[n], xv[n][m][1], fmaf(ar, accR[m][n][1], fmaf(acw[m][1], accC[m][n][1], ar * acw[m][1] * tb)));
            o[2] = fmaf(al[n], xv[n][m][2], fmaf(ar, accR[m][n][2], fmaf(acw[m][2], accC[m][n][2], ar * acw[m][2] * tb)));
            o[3] = fmaf(al[n], xv[n][m][3], fmaf(ar, accR[m][n][3], fmaf(acw[m][3], accC[m][n][3], ar * acw[m][3] * tb)));
            *(f32x4*)&out[rowb[n] + 16 * m] = o;
        }
    }
}

extern "C" void kernel_launch(void* const* d_in, const int* in_sizes, int n_in,
                              void* d_out, int out_size, void* d_ws, size_t ws_size,
                              hipStream_t stream) {
    const float* x        = (const float*)d_in[0];
    const float* U        = (const float*)d_in[1];
    const float* S        = (const float*)d_in[2];
    const float* V        = (const float*)d_in[3];
    const float* G        = (const float*)d_in[4];
    const float* w_row    = (const float*)d_in[5];
    const float* w_col    = (const float*)d_in[6];
    const float* boast    = (const float*)d_in[7];
    const float* res_scale= (const float*)d_in[8];
    const float* reduce_w = (const float*)d_in[9];
    const float* gcn_w    = (const float*)d_in[10];
    const float* gcn_b    = (const float*)d_in[11];
    const float* expand_w = (const float*)d_in[12];
    float* ws = (float*)d_ws;
    float* out = (float*)d_out;

    float* Xnode = ws + O_XNODE;
    float* Tg    = ws + O_T;
    ushort* Rh   = (ushort*)(ws + O_R);
    ushort* Ch   = (ushort*)(ws + O_CTX);
    ushort* Gb   = (ushort*)(ws + O_GT);
    float* attr  = ws + O_ATTR;
    float* attc  = ws + O_ATTC;
    float* Un    = ws + O_UN;
    float* sup   = ws + O_SUP;
    float* vals  = ws + O_VALS;
    float* deg   = ws + O_DEG;
    float* Usum  = ws + O_USUM;
    float* tmsum = ws + O_TMSUM;
    float* tm    = ws + O_TM;
    float* sigmt = ws + O_SIGMT;
    float* alpha = ws + O_ALPHA;
    float* sc    = ws + O_SC;
    float* arow  = ws + O_AROW;
    float* acol  = ws + O_ACOL;
    int*   idxv  = (int*)(ws + O_IDX);

    kA<<<1024 + BB * CC * HH / 4, 256, 0, stream>>>(x, Xnode, G, Gb);
    kS1<<<BB * HH, 64, 0, stream>>>(U, Xnode, reduce_w, gcn_w, Un, Usum, sup);
    kS2<<<BB * HH, 128, 0, stream>>>(Un, vals, idxv, deg);
    kS3<<<BB * HH, 64, 0, stream>>>(vals, idxv, deg, sup, gcn_b, expand_w, Tg, tmsum, sigmt);
    kS4<<<BB, 256, 0, stream>>>(Xnode, Tg, V, S, boast, res_scale, w_row, w_col, tmsum,
                                tm, alpha, sc, arow, acol);
    kS5<<<BB * HH + BB * WW, 128, 0, stream>>>(Usum, w_row, w_col, tm, attr, attc);
    kR<<<BB * CC, 256, 0, stream>>>(x, attr, attc, Rh, Ch);
    kF<<<dim3(PP / 128, CC / 64, BB), 256, 0, stream>>>(x, Rh, Ch, Gb, Tg, alpha, sc, sigmt,
                                                        arow, acol, out);
}